// Round 14
// baseline (60.085 us; speedup 1.0000x reference)
//
#include <hip/hip_runtime.h>

#define H_ 128
#define W_ 128
#define HW 16384
#define C_ 64
#define O_ 64
#define N_ 8

typedef __attribute__((ext_vector_type(4))) float f32x4;
typedef __attribute__((ext_vector_type(2))) _Float16 f16x2;
typedef __attribute__((ext_vector_type(8))) _Float16 f16x8;

__device__ __forceinline__ unsigned short f2h(float f) {
    union { _Float16 h; unsigned short u; } c;
    c.h = (_Float16)f;
    return c.u;
}

// ---- fused prep: [0,4096) nchw->nhwc f16 ; [4096,8704) tap plan ; [8704,8848) bpack ----
// Section offsets are multiples of 8 so the bid&7 XCD pinning survives.
// Plan geometry matches the 16(w)x8(h) main tile: t = ho&~7, tx0 = wo&~15,
// halo 20(y)x28(x), margin 6, k00 row stride 28 positions (dy step 112).
// (Plan encoding is h-independent; main converts to 8-chunk indices itself.)
__global__ __launch_bounds__(256) void prep_all(const float* __restrict__ x,
                                                const float* __restrict__ off,
                                                const float* __restrict__ w,
                                                unsigned short* __restrict__ xt,
                                                unsigned short* __restrict__ bp,
                                                unsigned* __restrict__ metap,
                                                unsigned* __restrict__ w01p,
                                                unsigned* __restrict__ w23p) {
    __shared__ unsigned short tile[32][65];
    const int bid = blockIdx.x;
    const int tid = threadIdx.x;

    if (bid < 4096) {
        // ---- NCHW fp32 -> NHWC f16 (XCD-aligned: n = bid&7) ----
        const int n = bid & 7;
        const int rest = bid >> 3;
        const int wt = rest & 3, h = rest >> 2;
        const int w0 = wt * 32;
        const int wl = tid & 31, cg = tid >> 5;
#pragma unroll
        for (int r = 0; r < 8; ++r) {
            const int c = cg * 8 + r;
            const float v = x[(((size_t)(n * 64 + c) * 128 + h) * 128) + w0 + wl];
            tile[wl][c] = f2h(v);
        }
        __syncthreads();
        const int c2 = tid & 63, wg = tid >> 6;
#pragma unroll
        for (int r = 0; r < 8; ++r) {
            const int ww = wg * 8 + r;
            xt[(((size_t)(n * 128 + h) * 128 + w0 + ww) << 6) + c2] = tile[ww][c2];
        }
    } else if (bid < 8704) {
        // ---- tap plan (16x8 tile geometry) ----
        // ok (bit31=1): meta = 0x80000000 | k00(bits0-11) | dx<<12 | dy<<13
        //   k00 = ((sy0*28+sx0)<<2) | (sx0&3)
        // !ok: meta = gpos<<16 | dx<<1 | dy  (low 12 bits zero -> speculative LDS read in-bounds)
        const int lbid = bid - 4096;       // 4608 = 8n * 9j * 64 pixblocks
        const int n = lbid & 7;
        const int rem = lbid >> 3;
        const int j = rem >> 6;
        const int pix = ((rem & 63) << 8) + tid;
        const int kh = j / 3, kw = j - kh * 3;
        const int ho = pix >> 7, wo = pix & 127;

        const float* ob = off + (size_t)(n * 18 + 2 * j) * HW + pix;
        const float oy = ob[0];
        const float ox = ob[HW];
        const float py = (float)(ho - 1 + kh) + oy;
        const float px = (float)(wo - 1 + kw) + ox;
        const float y0f = floorf(py), x0f = floorf(px);
        const float wy = py - y0f, wx = px - x0f;
        const int y0 = (int)y0f, x0 = (int)x0f;
        const bool vy0 = (unsigned)y0 < 128u;
        const bool vy1 = (unsigned)(y0 + 1) < 128u;
        const bool vx0 = (unsigned)x0 < 128u;
        const bool vx1 = (unsigned)(x0 + 1) < 128u;
        const int y0c = min(max(y0, 0), 127), y1c = min(max(y0 + 1, 0), 127);
        const int x0c = min(max(x0, 0), 127), x1c = min(max(x0 + 1, 0), 127);
        const float s00 = (1.f - wy) * (1.f - wx) * ((vy0 & vx0) ? 1.f : 0.f);
        const float s01 = (1.f - wy) * wx * ((vy0 & vx1) ? 1.f : 0.f);
        const float s10 = wy * (1.f - wx) * ((vy1 & vx0) ? 1.f : 0.f);
        const float s11 = wy * wx * ((vy1 & vx1) ? 1.f : 0.f);

        const int t = ho & ~7, tx0 = wo & ~15;
        const int sy0 = y0c - t + 6, sy1 = y1c - t + 6;
        const int sx0 = x0c - tx0 + 6, sx1 = x1c - tx0 + 6;
        const bool ok = ((unsigned)sy0 <= 19u) & ((unsigned)sy1 <= 19u) &
                        ((unsigned)sx0 <= 27u) & ((unsigned)sx1 <= 27u);
        unsigned meta;
        if (ok) {
            const unsigned k00 = ((unsigned)(sy0 * 28 + sx0) << 2) | (unsigned)(sx0 & 3);
            meta = 0x80000000u | k00 | ((unsigned)(x1c - x0c) << 12) | ((unsigned)(y1c - y0c) << 13);
        } else {
            meta = ((unsigned)(y0c * 128 + x0c) << 16) | ((unsigned)(x1c - x0c) << 1) | (unsigned)(y1c - y0c);
        }
        const size_t e = (size_t)(n * 9 + j) * HW + pix;
        metap[e] = meta;
        w01p[e] = (unsigned)f2h(s00) | ((unsigned)f2h(s01) << 16);
        w23p[e] = (unsigned)f2h(s10) | ((unsigned)f2h(s11) << 16);
    } else {
        // ---- weight -> B-fragment pack ----
        const int idx = (bid - 8704) * 256 + tid;
        if (idx < 36864) {
            const int i = idx & 7;
            const int lane = (idx >> 3) & 63;
            const int ot = (idx >> 9) & 3;
            const int h = (idx >> 11) & 1;
            const int j = idx >> 12;
            const int o = ot * 16 + (lane & 15);
            const int c = h * 32 + (lane >> 4) * 8 + i;
            bp[idx] = f2h(w[(o * 64 + c) * 9 + j]);
        }
    }
}

// ---- main: 16(w)x8(h) tile, 512-thread block, FULL 64-ch halo staged once ----
// 1024 blocks x 8 waves; one wave = one 16-px row-strip. LDS 20*28*128B = 71,680B
// -> 2 blocks/CU = 16 waves/CU (same as r13) but: plan load + decode + weight
// perms ONCE per (strip,j) (was 2x, once per K-half), single stage+barrier
// phase (was 4 phases), 8 back-to-back ds_read_b128 per tap-pair (better ILP).
// LDS layout: position p -> 8 x 16B chunks at p*8 + (chunk ^ (rx&3));
// chunk = (h<<2)|lgrp, XOR touches only bits 0-1 so h-half = +4 on the slot.
__global__ __launch_bounds__(512, 4) void dcn_mfma(const unsigned short* __restrict__ xt,
                                                   const unsigned* __restrict__ metap,
                                                   const unsigned* __restrict__ w01p,
                                                   const unsigned* __restrict__ w23p,
                                                   const unsigned short* __restrict__ bp,
                                                   float* __restrict__ out) {
    __shared__ uint4 lds4[5600];   // 20*28 positions * 8 chunks = 71,680 B

    const int tid = threadIdx.x;
    const int lane = tid & 63;
    const int wid = tid >> 6;          // 0..7 -> row within tile
    const int lrow = lane & 15;
    const int lgrp = lane >> 4;

    const int bid = blockIdx.x;
    const int n = bid & 7;
    const int tile = bid >> 3;           // 0..127
    const int t   = (tile >> 3) << 3;    // 16 row-tiles of 8
    const int tx0 = (tile & 7) << 4;     // 8 col-tiles of 16

    const unsigned short* xn = xt + (size_t)n * (HW * 64);
    const unsigned char* xb = (const unsigned char*)xn;
    const f16x8* bg = (const f16x8*)bp;
    const size_t nplane = (size_t)n * 9 * HW;
    const unsigned* mp  = metap + nplane;
    const unsigned* wpa = w01p + nplane;
    const unsigned* wpb = w23p + nplane;

    // ---- stage full halo (64 ch), coalesced, x-swizzled ----
    for (int i = tid; i < 4480; i += 512) {
        const int pos = i >> 3, sub = i & 7;
        const int ry = pos / 28, rx = pos - ry * 28;
        const int gy = min(max(t - 6 + ry, 0), 127);
        const int gx = min(max(tx0 - 6 + rx, 0), 127);
        const uint4* src = (const uint4*)(xn + (((gy << 7) + gx) << 6));
        lds4[(pos << 3) + (sub ^ (rx & 3))] = src[sub];
    }
    __syncthreads();

    const int ho = t + wid;
    const int pixb = (ho << 7) + tx0 + lrow;

    f32x4 acc[4];
#pragma unroll
    for (int r = 0; r < 4; ++r) acc[r] = (f32x4){0.f, 0.f, 0.f, 0.f};

#pragma unroll 3
    for (int j = 0; j < 9; ++j) {
        const int e = j * HW + pixb;
        const unsigned meta = mp[e];
        const unsigned wab = wpa[e];
        const unsigned wcd = wpb[e];
        union { unsigned u; f16x2 h2; } W00, W01, W10, W11;
        W00.u = __builtin_amdgcn_perm(wab, wab, 0x01000100u);
        W01.u = __builtin_amdgcn_perm(wab, wab, 0x03020302u);
        W10.u = __builtin_amdgcn_perm(wcd, wcd, 0x01000100u);
        W11.u = __builtin_amdgcn_perm(wcd, wcd, 0x03020302u);

        const bool ok = (int)meta < 0;
        const unsigned k00 = meta & 0xfffu;
        const unsigned dx = (meta >> 12) & 1u;
        const unsigned k01 = ((k00 & ~3u) + (dx << 2)) | (((k00 & 3u) + dx) & 3u);
        const unsigned dyi = (meta & 0x2000u) ? 112u : 0u;
        const unsigned k10 = k00 + dyi, k11 = k01 + dyi;
        // old 4-chunk index k -> 8-chunk base: pos*8 + (lgrp ^ sxlow); h adds +4
        const unsigned b00 = ((k00 & ~3u) << 1) + ((unsigned)lgrp ^ (k00 & 3u));
        const unsigned b01 = ((k01 & ~3u) << 1) + ((unsigned)lgrp ^ (k01 & 3u));
        const unsigned b10 = ((k10 & ~3u) << 1) + ((unsigned)lgrp ^ (k10 & 3u));
        const unsigned b11 = ((k11 & ~3u) << 1) + ((unsigned)lgrp ^ (k11 & 3u));

        uint4 T00a = lds4[b00],     T01a = lds4[b01],     T10a = lds4[b10],     T11a = lds4[b11];
        uint4 T00b = lds4[b00 + 4], T01b = lds4[b01 + 4], T10b = lds4[b10 + 4], T11b = lds4[b11 + 4];
        if (!__all(ok)) {   // rare: tap beyond halo -> exact global path (both halves)
            if (!ok) {
                const unsigned gpos = (meta >> 16) & 0x3fffu;
                const int dxo = (int)((meta >> 1) & 1u) << 7;
                const int dyo = (int)(meta & 1u) << 14;
                const unsigned char* p = xb + (gpos << 7) + (lgrp << 4);
                T00a = *(const uint4*)p;              T00b = *(const uint4*)(p + 64);
                T01a = *(const uint4*)(p + dxo);      T01b = *(const uint4*)(p + dxo + 64);
                T10a = *(const uint4*)(p + dyo);      T10b = *(const uint4*)(p + dyo + 64);
                T11a = *(const uint4*)(p + dyo + dxo);T11b = *(const uint4*)(p + dyo + dxo + 64);
            }
        }
        const int fb0 = ((j * 2) << 8) + lane;
        {   // h = 0
            union { uint4 u; f16x2 h2[4]; f16x8 v; } A, U00, U01, U10, U11;
            U00.u = T00a; U01.u = T01a; U10.u = T10a; U11.u = T11a;
#pragma unroll
            for (int k = 0; k < 4; ++k)
                A.h2[k] = U00.h2[k] * W00.h2 + U01.h2[k] * W01.h2
                        + U10.h2[k] * W10.h2 + U11.h2[k] * W11.h2;
            acc[0] = __builtin_amdgcn_mfma_f32_16x16x32_f16(A.v, bg[fb0],       acc[0], 0, 0, 0);
            acc[1] = __builtin_amdgcn_mfma_f32_16x16x32_f16(A.v, bg[fb0 + 64],  acc[1], 0, 0, 0);
            acc[2] = __builtin_amdgcn_mfma_f32_16x16x32_f16(A.v, bg[fb0 + 128], acc[2], 0, 0, 0);
            acc[3] = __builtin_amdgcn_mfma_f32_16x16x32_f16(A.v, bg[fb0 + 192], acc[3], 0, 0, 0);
        }
        {   // h = 1
            union { uint4 u; f16x2 h2[4]; f16x8 v; } A, U00, U01, U10, U11;
            U00.u = T00b; U01.u = T01b; U10.u = T10b; U11.u = T11b;
#pragma unroll
            for (int k = 0; k < 4; ++k)
                A.h2[k] = U00.h2[k] * W00.h2 + U01.h2[k] * W01.h2
                        + U10.h2[k] * W10.h2 + U11.h2[k] * W11.h2;
            acc[0] = __builtin_amdgcn_mfma_f32_16x16x32_f16(A.v, bg[fb0 + 256], acc[0], 0, 0, 0);
            acc[1] = __builtin_amdgcn_mfma_f32_16x16x32_f16(A.v, bg[fb0 + 320], acc[1], 0, 0, 0);
            acc[2] = __builtin_amdgcn_mfma_f32_16x16x32_f16(A.v, bg[fb0 + 384], acc[2], 0, 0, 0);
            acc[3] = __builtin_amdgcn_mfma_f32_16x16x32_f16(A.v, bg[fb0 + 448], acc[3], 0, 0, 0);
        }
    }

    // epilogue: o = qq*16 + lrow plane, pixel = tx0 + lgrp*4 + r (layout validated r2-r13)
    float* opb = out + (size_t)n * (O_ * HW) + ((size_t)ho << 7) + tx0 + lgrp * 4;
#pragma unroll
    for (int qq = 0; qq < 4; ++qq)
        *(f32x4*)(opb + (size_t)(qq * 16 + lrow) * HW) = acc[qq];
}

extern "C" void kernel_launch(void* const* d_in, const int* in_sizes, int n_in,
                              void* d_out, int out_size, void* d_ws, size_t ws_size,
                              hipStream_t stream) {
    const float* x = (const float*)d_in[0];
    const float* off = (const float*)d_in[1];
    const float* w = (const float*)d_in[2];
    float* out = (float*)d_out;

    char* ws = (char*)d_ws;
    unsigned short* bp = (unsigned short*)ws;                       //      73,728 B
    unsigned short* xt = (unsigned short*)(ws + 73728);             //  16,777,216 B
    unsigned* metap = (unsigned*)(ws + 16850944);                   //   4,718,592 B
    unsigned* w01p  = (unsigned*)(ws + 21569536);                   //   4,718,592 B
    unsigned* w23p  = (unsigned*)(ws + 26288128);                   //   4,718,592 B -> 31.0 MB

    prep_all<<<8848, 256, 0, stream>>>(x, off, w, xt, bp, metap, w01p, w23p);
    dcn_mfma<<<1024, 512, 0, stream>>>(xt, metap, w01p, w23p, bp, out);
}

// Round 15
// 49.882 us; speedup vs baseline: 1.2045x; 1.2045x over previous
//
#include <hip/hip_runtime.h>

#define H_ 128
#define W_ 128
#define HW 16384
#define C_ 64
#define O_ 64
#define N_ 8

typedef __attribute__((ext_vector_type(4))) float f32x4;
typedef __attribute__((ext_vector_type(2))) _Float16 f16x2;
typedef __attribute__((ext_vector_type(8))) _Float16 f16x8;

__device__ __forceinline__ unsigned short f2h(float f) {
    union { _Float16 h; unsigned short u; } c;
    c.h = (_Float16)f;
    return c.u;
}

// ---- fused prep: [0,4096) nchw->nhwc f16 ; [4096,8704) tap plan ; [8704,8848) bpack ----
// Section offsets are multiples of 8 so the bid&7 XCD pinning survives.
// Plan geometry matches the 16(w)x8(h) main tile: t = ho&~7, tx0 = wo&~15,
// halo 20(y)x28(x), margin 6, k00 row stride 28 positions (dy step 112).
__global__ __launch_bounds__(256) void prep_all(const float* __restrict__ x,
                                                const float* __restrict__ off,
                                                const float* __restrict__ w,
                                                unsigned short* __restrict__ xt,
                                                unsigned short* __restrict__ bp,
                                                unsigned* __restrict__ metap,
                                                unsigned* __restrict__ w01p,
                                                unsigned* __restrict__ w23p) {
    __shared__ unsigned short tile[32][65];
    const int bid = blockIdx.x;
    const int tid = threadIdx.x;

    if (bid < 4096) {
        // ---- NCHW fp32 -> NHWC f16 (XCD-aligned: n = bid&7) ----
        const int n = bid & 7;
        const int rest = bid >> 3;
        const int wt = rest & 3, h = rest >> 2;
        const int w0 = wt * 32;
        const int wl = tid & 31, cg = tid >> 5;
#pragma unroll
        for (int r = 0; r < 8; ++r) {
            const int c = cg * 8 + r;
            const float v = x[(((size_t)(n * 64 + c) * 128 + h) * 128) + w0 + wl];
            tile[wl][c] = f2h(v);
        }
        __syncthreads();
        const int c2 = tid & 63, wg = tid >> 6;
#pragma unroll
        for (int r = 0; r < 8; ++r) {
            const int ww = wg * 8 + r;
            xt[(((size_t)(n * 128 + h) * 128 + w0 + ww) << 6) + c2] = tile[ww][c2];
        }
    } else if (bid < 8704) {
        // ---- tap plan (16x8 tile geometry) ----
        // ok (bit31=1): meta = 0x80000000 | k00(bits0-11) | dx<<12 | dy<<13
        //   k00 = ((sy0*28+sx0)<<2) | (sx0&3)
        // !ok: meta = gpos<<16 | dx<<1 | dy  (low 12 bits zero -> speculative LDS read in-bounds)
        const int lbid = bid - 4096;       // 4608 = 8n * 9j * 64 pixblocks
        const int n = lbid & 7;
        const int rem = lbid >> 3;
        const int j = rem >> 6;
        const int pix = ((rem & 63) << 8) + tid;
        const int kh = j / 3, kw = j - kh * 3;
        const int ho = pix >> 7, wo = pix & 127;

        const float* ob = off + (size_t)(n * 18 + 2 * j) * HW + pix;
        const float oy = ob[0];
        const float ox = ob[HW];
        const float py = (float)(ho - 1 + kh) + oy;
        const float px = (float)(wo - 1 + kw) + ox;
        const float y0f = floorf(py), x0f = floorf(px);
        const float wy = py - y0f, wx = px - x0f;
        const int y0 = (int)y0f, x0 = (int)x0f;
        const bool vy0 = (unsigned)y0 < 128u;
        const bool vy1 = (unsigned)(y0 + 1) < 128u;
        const bool vx0 = (unsigned)x0 < 128u;
        const bool vx1 = (unsigned)(x0 + 1) < 128u;
        const int y0c = min(max(y0, 0), 127), y1c = min(max(y0 + 1, 0), 127);
        const int x0c = min(max(x0, 0), 127), x1c = min(max(x0 + 1, 0), 127);
        const float s00 = (1.f - wy) * (1.f - wx) * ((vy0 & vx0) ? 1.f : 0.f);
        const float s01 = (1.f - wy) * wx * ((vy0 & vx1) ? 1.f : 0.f);
        const float s10 = wy * (1.f - wx) * ((vy1 & vx0) ? 1.f : 0.f);
        const float s11 = wy * wx * ((vy1 & vx1) ? 1.f : 0.f);

        const int t = ho & ~7, tx0 = wo & ~15;
        const int sy0 = y0c - t + 6, sy1 = y1c - t + 6;
        const int sx0 = x0c - tx0 + 6, sx1 = x1c - tx0 + 6;
        const bool ok = ((unsigned)sy0 <= 19u) & ((unsigned)sy1 <= 19u) &
                        ((unsigned)sx0 <= 27u) & ((unsigned)sx1 <= 27u);
        unsigned meta;
        if (ok) {
            const unsigned k00 = ((unsigned)(sy0 * 28 + sx0) << 2) | (unsigned)(sx0 & 3);
            meta = 0x80000000u | k00 | ((unsigned)(x1c - x0c) << 12) | ((unsigned)(y1c - y0c) << 13);
        } else {
            meta = ((unsigned)(y0c * 128 + x0c) << 16) | ((unsigned)(x1c - x0c) << 1) | (unsigned)(y1c - y0c);
        }
        const size_t e = (size_t)(n * 9 + j) * HW + pix;
        metap[e] = meta;
        w01p[e] = (unsigned)f2h(s00) | ((unsigned)f2h(s01) << 16);
        w23p[e] = (unsigned)f2h(s10) | ((unsigned)f2h(s11) << 16);
    } else {
        // ---- weight -> B-fragment pack ----
        const int idx = (bid - 8704) * 256 + tid;
        if (idx < 36864) {
            const int i = idx & 7;
            const int lane = (idx >> 3) & 63;
            const int ot = (idx >> 9) & 3;
            const int h = (idx >> 11) & 1;
            const int j = idx >> 12;
            const int o = ot * 16 + (lane & 15);
            const int c = h * 32 + (lane >> 4) * 8 + i;
            bp[idx] = f2h(w[(o * 64 + c) * 9 + j]);
        }
    }
}

// ---- main: 16(w)x8(h) tile, 512-thread block, FULL 64-ch halo staged once ----
// 1024 blocks x 8 waves; one wave = one 16-px row-strip.
// LDS = 20*28 positions x 8 chunks x 16B = 4480 uint4 = 71,680 B -> 2 blocks/CU
// (r14 bug: declared 5600 uint4 = 89.6KB > 80KB -> 1 block/CU, occupancy 17%.)
// Plan load + decode + weight perms once per (strip,j); h-half = +4 chunk slots.
// LDS layout: position p -> 8 chunks at p*8 + ((h<<2 | lgrp) ^ (rx&3)); the
// 2-bit XOR never touches bit 2, so +4 selects the h=1 half exactly.
__global__ __launch_bounds__(512, 4) void dcn_mfma(const unsigned short* __restrict__ xt,
                                                   const unsigned* __restrict__ metap,
                                                   const unsigned* __restrict__ w01p,
                                                   const unsigned* __restrict__ w23p,
                                                   const unsigned short* __restrict__ bp,
                                                   float* __restrict__ out) {
    __shared__ uint4 lds4[4480];   // 20*28 positions * 8 chunks = 71,680 B

    const int tid = threadIdx.x;
    const int lane = tid & 63;
    const int wid = tid >> 6;          // 0..7 -> row within tile
    const int lrow = lane & 15;
    const int lgrp = lane >> 4;

    const int bid = blockIdx.x;
    const int n = bid & 7;
    const int tile = bid >> 3;           // 0..127
    const int t   = (tile >> 3) << 3;    // 16 row-tiles of 8
    const int tx0 = (tile & 7) << 4;     // 8 col-tiles of 16

    const unsigned short* xn = xt + (size_t)n * (HW * 64);
    const unsigned char* xb = (const unsigned char*)xn;
    const f16x8* bg = (const f16x8*)bp;
    const size_t nplane = (size_t)n * 9 * HW;
    const unsigned* mp  = metap + nplane;
    const unsigned* wpa = w01p + nplane;
    const unsigned* wpb = w23p + nplane;

    // ---- stage full halo (64 ch), coalesced, x-swizzled ----
    for (int i = tid; i < 4480; i += 512) {
        const int pos = i >> 3, sub = i & 7;
        const int ry = pos / 28, rx = pos - ry * 28;
        const int gy = min(max(t - 6 + ry, 0), 127);
        const int gx = min(max(tx0 - 6 + rx, 0), 127);
        const uint4* src = (const uint4*)(xn + (((gy << 7) + gx) << 6));
        lds4[(pos << 3) + (sub ^ (rx & 3))] = src[sub];
    }
    __syncthreads();

    const int ho = t + wid;
    const int pixb = (ho << 7) + tx0 + lrow;

    f32x4 acc[4];
#pragma unroll
    for (int r = 0; r < 4; ++r) acc[r] = (f32x4){0.f, 0.f, 0.f, 0.f};

#pragma unroll 3
    for (int j = 0; j < 9; ++j) {
        const int e = j * HW + pixb;
        const unsigned meta = mp[e];
        const unsigned wab = wpa[e];
        const unsigned wcd = wpb[e];
        union { unsigned u; f16x2 h2; } W00, W01, W10, W11;
        W00.u = __builtin_amdgcn_perm(wab, wab, 0x01000100u);
        W01.u = __builtin_amdgcn_perm(wab, wab, 0x03020302u);
        W10.u = __builtin_amdgcn_perm(wcd, wcd, 0x01000100u);
        W11.u = __builtin_amdgcn_perm(wcd, wcd, 0x03020302u);

        const bool ok = (int)meta < 0;
        const unsigned k00 = meta & 0xfffu;
        const unsigned dx = (meta >> 12) & 1u;
        const unsigned k01 = ((k00 & ~3u) + (dx << 2)) | (((k00 & 3u) + dx) & 3u);
        const unsigned dyi = (meta & 0x2000u) ? 112u : 0u;
        const unsigned k10 = k00 + dyi, k11 = k01 + dyi;
        // old 4-chunk index k -> 8-chunk base: pos*8 + (lgrp ^ sxlow); h adds +4
        const unsigned b00 = ((k00 & ~3u) << 1) + ((unsigned)lgrp ^ (k00 & 3u));
        const unsigned b01 = ((k01 & ~3u) << 1) + ((unsigned)lgrp ^ (k01 & 3u));
        const unsigned b10 = ((k10 & ~3u) << 1) + ((unsigned)lgrp ^ (k10 & 3u));
        const unsigned b11 = ((k11 & ~3u) << 1) + ((unsigned)lgrp ^ (k11 & 3u));

        uint4 T00a = lds4[b00],     T01a = lds4[b01],     T10a = lds4[b10],     T11a = lds4[b11];
        uint4 T00b = lds4[b00 + 4], T01b = lds4[b01 + 4], T10b = lds4[b10 + 4], T11b = lds4[b11 + 4];
        if (!__all(ok)) {   // rare: tap beyond halo -> exact global path (both halves)
            if (!ok) {
                const unsigned gpos = (meta >> 16) & 0x3fffu;
                const int dxo = (int)((meta >> 1) & 1u) << 7;
                const int dyo = (int)(meta & 1u) << 14;
                const unsigned char* p = xb + (gpos << 7) + (lgrp << 4);
                T00a = *(const uint4*)p;              T00b = *(const uint4*)(p + 64);
                T01a = *(const uint4*)(p + dxo);      T01b = *(const uint4*)(p + dxo + 64);
                T10a = *(const uint4*)(p + dyo);      T10b = *(const uint4*)(p + dyo + 64);
                T11a = *(const uint4*)(p + dyo + dxo);T11b = *(const uint4*)(p + dyo + dxo + 64);
            }
        }
        const int fb0 = ((j * 2) << 8) + lane;
        {   // h = 0
            union { uint4 u; f16x2 h2[4]; f16x8 v; } A, U00, U01, U10, U11;
            U00.u = T00a; U01.u = T01a; U10.u = T10a; U11.u = T11a;
#pragma unroll
            for (int k = 0; k < 4; ++k)
                A.h2[k] = U00.h2[k] * W00.h2 + U01.h2[k] * W01.h2
                        + U10.h2[k] * W10.h2 + U11.h2[k] * W11.h2;
            acc[0] = __builtin_amdgcn_mfma_f32_16x16x32_f16(A.v, bg[fb0],       acc[0], 0, 0, 0);
            acc[1] = __builtin_amdgcn_mfma_f32_16x16x32_f16(A.v, bg[fb0 + 64],  acc[1], 0, 0, 0);
            acc[2] = __builtin_amdgcn_mfma_f32_16x16x32_f16(A.v, bg[fb0 + 128], acc[2], 0, 0, 0);
            acc[3] = __builtin_amdgcn_mfma_f32_16x16x32_f16(A.v, bg[fb0 + 192], acc[3], 0, 0, 0);
        }
        {   // h = 1
            union { uint4 u; f16x2 h2[4]; f16x8 v; } A, U00, U01, U10, U11;
            U00.u = T00b; U01.u = T01b; U10.u = T10b; U11.u = T11b;
#pragma unroll
            for (int k = 0; k < 4; ++k)
                A.h2[k] = U00.h2[k] * W00.h2 + U01.h2[k] * W01.h2
                        + U10.h2[k] * W10.h2 + U11.h2[k] * W11.h2;
            acc[0] = __builtin_amdgcn_mfma_f32_16x16x32_f16(A.v, bg[fb0 + 256], acc[0], 0, 0, 0);
            acc[1] = __builtin_amdgcn_mfma_f32_16x16x32_f16(A.v, bg[fb0 + 320], acc[1], 0, 0, 0);
            acc[2] = __builtin_amdgcn_mfma_f32_16x16x32_f16(A.v, bg[fb0 + 384], acc[2], 0, 0, 0);
            acc[3] = __builtin_amdgcn_mfma_f32_16x16x32_f16(A.v, bg[fb0 + 448], acc[3], 0, 0, 0);
        }
    }

    // epilogue: o = qq*16 + lrow plane, pixel = tx0 + lgrp*4 + r (layout validated r2-r14)
    float* opb = out + (size_t)n * (O_ * HW) + ((size_t)ho << 7) + tx0 + lgrp * 4;
#pragma unroll
    for (int qq = 0; qq < 4; ++qq)
        *(f32x4*)(opb + (size_t)(qq * 16 + lrow) * HW) = acc[qq];
}

extern "C" void kernel_launch(void* const* d_in, const int* in_sizes, int n_in,
                              void* d_out, int out_size, void* d_ws, size_t ws_size,
                              hipStream_t stream) {
    const float* x = (const float*)d_in[0];
    const float* off = (const float*)d_in[1];
    const float* w = (const float*)d_in[2];
    float* out = (float*)d_out;

    char* ws = (char*)d_ws;
    unsigned short* bp = (unsigned short*)ws;                       //      73,728 B
    unsigned short* xt = (unsigned short*)(ws + 73728);             //  16,777,216 B
    unsigned* metap = (unsigned*)(ws + 16850944);                   //   4,718,592 B
    unsigned* w01p  = (unsigned*)(ws + 21569536);                   //   4,718,592 B
    unsigned* w23p  = (unsigned*)(ws + 26288128);                   //   4,718,592 B -> 31.0 MB

    prep_all<<<8848, 256, 0, stream>>>(x, off, w, xt, bp, metap, w01p, w23p);
    dcn_mfma<<<1024, 512, 0, stream>>>(xt, metap, w01p, w23p, bp, out);
}

// Round 16
// 48.507 us; speedup vs baseline: 1.2387x; 1.0283x over previous
//
#include <hip/hip_runtime.h>

#define H_ 128
#define W_ 128
#define HW 16384
#define C_ 64
#define O_ 64
#define N_ 8

typedef __attribute__((ext_vector_type(4))) float f32x4;
typedef __attribute__((ext_vector_type(2))) _Float16 f16x2;
typedef __attribute__((ext_vector_type(8))) _Float16 f16x8;

__device__ __forceinline__ unsigned short f2h(float f) {
    union { _Float16 h; unsigned short u; } c;
    c.h = (_Float16)f;
    return c.u;
}

// ---- fused prep: [0,4096) nchw->nhwc f16 ; [4096,8704) tap plan ; [8704,8848) bpack ----
// Section offsets are multiples of 8 so the bid&7 XCD pinning survives.
// Plan geometry matches the 16(w)x8(h) main tile: t = ho&~7, tx0 = wo&~15,
// halo 20(y)x28(x), margin 6, k00 row stride 28 positions (dy step 112).
__global__ __launch_bounds__(256) void prep_all(const float* __restrict__ x,
                                                const float* __restrict__ off,
                                                const float* __restrict__ w,
                                                unsigned short* __restrict__ xt,
                                                unsigned short* __restrict__ bp,
                                                unsigned* __restrict__ metap,
                                                unsigned* __restrict__ w01p,
                                                unsigned* __restrict__ w23p) {
    __shared__ unsigned short tile[32][65];
    const int bid = blockIdx.x;
    const int tid = threadIdx.x;

    if (bid < 4096) {
        // ---- NCHW fp32 -> NHWC f16 (XCD-aligned: n = bid&7) ----
        const int n = bid & 7;
        const int rest = bid >> 3;
        const int wt = rest & 3, h = rest >> 2;
        const int w0 = wt * 32;
        const int wl = tid & 31, cg = tid >> 5;
#pragma unroll
        for (int r = 0; r < 8; ++r) {
            const int c = cg * 8 + r;
            const float v = x[(((size_t)(n * 64 + c) * 128 + h) * 128) + w0 + wl];
            tile[wl][c] = f2h(v);
        }
        __syncthreads();
        const int c2 = tid & 63, wg = tid >> 6;
#pragma unroll
        for (int r = 0; r < 8; ++r) {
            const int ww = wg * 8 + r;
            xt[(((size_t)(n * 128 + h) * 128 + w0 + ww) << 6) + c2] = tile[ww][c2];
        }
    } else if (bid < 8704) {
        // ---- tap plan (16x8 tile geometry) ----
        // ok (bit31=1): meta = 0x80000000 | k00(bits0-11) | dx<<12 | dy<<13
        //   k00 = ((sy0*28+sx0)<<2) | (sx0&3)
        // !ok: meta = gpos<<16 | dx<<1 | dy  (low 12 bits zero -> speculative LDS read in-bounds)
        const int lbid = bid - 4096;       // 4608 = 8n * 9j * 64 pixblocks
        const int n = lbid & 7;
        const int rem = lbid >> 3;
        const int j = rem >> 6;
        const int pix = ((rem & 63) << 8) + tid;
        const int kh = j / 3, kw = j - kh * 3;
        const int ho = pix >> 7, wo = pix & 127;

        const float* ob = off + (size_t)(n * 18 + 2 * j) * HW + pix;
        const float oy = ob[0];
        const float ox = ob[HW];
        const float py = (float)(ho - 1 + kh) + oy;
        const float px = (float)(wo - 1 + kw) + ox;
        const float y0f = floorf(py), x0f = floorf(px);
        const float wy = py - y0f, wx = px - x0f;
        const int y0 = (int)y0f, x0 = (int)x0f;
        const bool vy0 = (unsigned)y0 < 128u;
        const bool vy1 = (unsigned)(y0 + 1) < 128u;
        const bool vx0 = (unsigned)x0 < 128u;
        const bool vx1 = (unsigned)(x0 + 1) < 128u;
        const int y0c = min(max(y0, 0), 127), y1c = min(max(y0 + 1, 0), 127);
        const int x0c = min(max(x0, 0), 127), x1c = min(max(x0 + 1, 0), 127);
        const float s00 = (1.f - wy) * (1.f - wx) * ((vy0 & vx0) ? 1.f : 0.f);
        const float s01 = (1.f - wy) * wx * ((vy0 & vx1) ? 1.f : 0.f);
        const float s10 = wy * (1.f - wx) * ((vy1 & vx0) ? 1.f : 0.f);
        const float s11 = wy * wx * ((vy1 & vx1) ? 1.f : 0.f);

        const int t = ho & ~7, tx0 = wo & ~15;
        const int sy0 = y0c - t + 6, sy1 = y1c - t + 6;
        const int sx0 = x0c - tx0 + 6, sx1 = x1c - tx0 + 6;
        const bool ok = ((unsigned)sy0 <= 19u) & ((unsigned)sy1 <= 19u) &
                        ((unsigned)sx0 <= 27u) & ((unsigned)sx1 <= 27u);
        unsigned meta;
        if (ok) {
            const unsigned k00 = ((unsigned)(sy0 * 28 + sx0) << 2) | (unsigned)(sx0 & 3);
            meta = 0x80000000u | k00 | ((unsigned)(x1c - x0c) << 12) | ((unsigned)(y1c - y0c) << 13);
        } else {
            meta = ((unsigned)(y0c * 128 + x0c) << 16) | ((unsigned)(x1c - x0c) << 1) | (unsigned)(y1c - y0c);
        }
        const size_t e = (size_t)(n * 9 + j) * HW + pix;
        metap[e] = meta;
        w01p[e] = (unsigned)f2h(s00) | ((unsigned)f2h(s01) << 16);
        w23p[e] = (unsigned)f2h(s10) | ((unsigned)f2h(s11) << 16);
    } else {
        // ---- weight -> B-fragment pack ----
        const int idx = (bid - 8704) * 256 + tid;
        if (idx < 36864) {
            const int i = idx & 7;
            const int lane = (idx >> 3) & 63;
            const int ot = (idx >> 9) & 3;
            const int h = (idx >> 11) & 1;
            const int j = idx >> 12;
            const int o = ot * 16 + (lane & 15);
            const int c = h * 32 + (lane >> 4) * 8 + i;
            bp[idx] = f2h(w[(o * 64 + c) * 9 + j]);
        }
    }
}

// ---- main: 16(w)x8(h) tile, 512-thread block, FULL 64-ch halo staged once ----
// 1024 blocks x 8 waves; one wave = one 16-px row-strip; LDS 71,680B -> 2 blk/CU.
// r16 change: ALL 9 taps' plan words preloaded into registers before the j-loop
// and the j-loop fully unrolled -- plan-load latency (L2, ~200cy) overlaps prior
// taps' LDS+MFMA instead of stalling at unroll-3 distance. Arrays fully
// unrolled => compile-time indices => SROA to registers (no scratch).
__global__ __launch_bounds__(512, 4) void dcn_mfma(const unsigned short* __restrict__ xt,
                                                   const unsigned* __restrict__ metap,
                                                   const unsigned* __restrict__ w01p,
                                                   const unsigned* __restrict__ w23p,
                                                   const unsigned short* __restrict__ bp,
                                                   float* __restrict__ out) {
    __shared__ uint4 lds4[4480];   // 20*28 positions * 8 chunks = 71,680 B

    const int tid = threadIdx.x;
    const int lane = tid & 63;
    const int wid = tid >> 6;          // 0..7 -> row within tile
    const int lrow = lane & 15;
    const int lgrp = lane >> 4;

    const int bid = blockIdx.x;
    const int n = bid & 7;
    const int tile = bid >> 3;           // 0..127
    const int t   = (tile >> 3) << 3;    // 16 row-tiles of 8
    const int tx0 = (tile & 7) << 4;     // 8 col-tiles of 16

    const unsigned short* xn = xt + (size_t)n * (HW * 64);
    const unsigned char* xb = (const unsigned char*)xn;
    const f16x8* bg = (const f16x8*)bp;
    const size_t nplane = (size_t)n * 9 * HW;
    const unsigned* mp  = metap + nplane;
    const unsigned* wpa = w01p + nplane;
    const unsigned* wpb = w23p + nplane;

    const int ho = t + wid;
    const int pixb = (ho << 7) + tx0 + lrow;

    // ---- preload all 9 taps' plan data (overlaps with halo staging below) ----
    unsigned mt[9], wa[9], wb[9];
#pragma unroll
    for (int j = 0; j < 9; ++j) {
        const int e = j * HW + pixb;
        mt[j] = mp[e];
        wa[j] = wpa[e];
        wb[j] = wpb[e];
    }

    // ---- stage full halo (64 ch), coalesced, x-swizzled ----
    for (int i = tid; i < 4480; i += 512) {
        const int pos = i >> 3, sub = i & 7;
        const int ry = pos / 28, rx = pos - ry * 28;
        const int gy = min(max(t - 6 + ry, 0), 127);
        const int gx = min(max(tx0 - 6 + rx, 0), 127);
        const uint4* src = (const uint4*)(xn + (((gy << 7) + gx) << 6));
        lds4[(pos << 3) + (sub ^ (rx & 3))] = src[sub];
    }
    __syncthreads();

    f32x4 acc[4];
#pragma unroll
    for (int r = 0; r < 4; ++r) acc[r] = (f32x4){0.f, 0.f, 0.f, 0.f};

#pragma unroll
    for (int j = 0; j < 9; ++j) {
        const unsigned meta = mt[j];
        const unsigned wab = wa[j];
        const unsigned wcd = wb[j];
        union { unsigned u; f16x2 h2; } W00, W01, W10, W11;
        W00.u = __builtin_amdgcn_perm(wab, wab, 0x01000100u);
        W01.u = __builtin_amdgcn_perm(wab, wab, 0x03020302u);
        W10.u = __builtin_amdgcn_perm(wcd, wcd, 0x01000100u);
        W11.u = __builtin_amdgcn_perm(wcd, wcd, 0x03020302u);

        const bool ok = (int)meta < 0;
        const unsigned k00 = meta & 0xfffu;
        const unsigned dx = (meta >> 12) & 1u;
        const unsigned k01 = ((k00 & ~3u) + (dx << 2)) | (((k00 & 3u) + dx) & 3u);
        const unsigned dyi = (meta & 0x2000u) ? 112u : 0u;
        const unsigned k10 = k00 + dyi, k11 = k01 + dyi;
        // 4-chunk index k -> 8-chunk base: pos*8 + (lgrp ^ sxlow); h adds +4
        const unsigned b00 = ((k00 & ~3u) << 1) + ((unsigned)lgrp ^ (k00 & 3u));
        const unsigned b01 = ((k01 & ~3u) << 1) + ((unsigned)lgrp ^ (k01 & 3u));
        const unsigned b10 = ((k10 & ~3u) << 1) + ((unsigned)lgrp ^ (k10 & 3u));
        const unsigned b11 = ((k11 & ~3u) << 1) + ((unsigned)lgrp ^ (k11 & 3u));

        uint4 T00a = lds4[b00],     T01a = lds4[b01],     T10a = lds4[b10],     T11a = lds4[b11];
        uint4 T00b = lds4[b00 + 4], T01b = lds4[b01 + 4], T10b = lds4[b10 + 4], T11b = lds4[b11 + 4];
        if (!__all(ok)) {   // rare: tap beyond halo -> exact global path (both halves)
            if (!ok) {
                const unsigned gpos = (meta >> 16) & 0x3fffu;
                const int dxo = (int)((meta >> 1) & 1u) << 7;
                const int dyo = (int)(meta & 1u) << 14;
                const unsigned char* p = xb + (gpos << 7) + (lgrp << 4);
                T00a = *(const uint4*)p;              T00b = *(const uint4*)(p + 64);
                T01a = *(const uint4*)(p + dxo);      T01b = *(const uint4*)(p + dxo + 64);
                T10a = *(const uint4*)(p + dyo);      T10b = *(const uint4*)(p + dyo + 64);
                T11a = *(const uint4*)(p + dyo + dxo);T11b = *(const uint4*)(p + dyo + dxo + 64);
            }
        }
        const int fb0 = ((j * 2) << 8) + lane;
        {   // h = 0
            union { uint4 u; f16x2 h2[4]; f16x8 v; } A, U00, U01, U10, U11;
            U00.u = T00a; U01.u = T01a; U10.u = T10a; U11.u = T11a;
#pragma unroll
            for (int k = 0; k < 4; ++k)
                A.h2[k] = U00.h2[k] * W00.h2 + U01.h2[k] * W01.h2
                        + U10.h2[k] * W10.h2 + U11.h2[k] * W11.h2;
            acc[0] = __builtin_amdgcn_mfma_f32_16x16x32_f16(A.v, bg[fb0],       acc[0], 0, 0, 0);
            acc[1] = __builtin_amdgcn_mfma_f32_16x16x32_f16(A.v, bg[fb0 + 64],  acc[1], 0, 0, 0);
            acc[2] = __builtin_amdgcn_mfma_f32_16x16x32_f16(A.v, bg[fb0 + 128], acc[2], 0, 0, 0);
            acc[3] = __builtin_amdgcn_mfma_f32_16x16x32_f16(A.v, bg[fb0 + 192], acc[3], 0, 0, 0);
        }
        {   // h = 1
            union { uint4 u; f16x2 h2[4]; f16x8 v; } A, U00, U01, U10, U11;
            U00.u = T00b; U01.u = T01b; U10.u = T10b; U11.u = T11b;
#pragma unroll
            for (int k = 0; k < 4; ++k)
                A.h2[k] = U00.h2[k] * W00.h2 + U01.h2[k] * W01.h2
                        + U10.h2[k] * W10.h2 + U11.h2[k] * W11.h2;
            acc[0] = __builtin_amdgcn_mfma_f32_16x16x32_f16(A.v, bg[fb0 + 256], acc[0], 0, 0, 0);
            acc[1] = __builtin_amdgcn_mfma_f32_16x16x32_f16(A.v, bg[fb0 + 320], acc[1], 0, 0, 0);
            acc[2] = __builtin_amdgcn_mfma_f32_16x16x32_f16(A.v, bg[fb0 + 384], acc[2], 0, 0, 0);
            acc[3] = __builtin_amdgcn_mfma_f32_16x16x32_f16(A.v, bg[fb0 + 448], acc[3], 0, 0, 0);
        }
    }

    // epilogue: o = qq*16 + lrow plane, pixel = tx0 + lgrp*4 + r (layout validated r2-r15)
    float* opb = out + (size_t)n * (O_ * HW) + ((size_t)ho << 7) + tx0 + lgrp * 4;
#pragma unroll
    for (int qq = 0; qq < 4; ++qq)
        *(f32x4*)(opb + (size_t)(qq * 16 + lrow) * HW) = acc[qq];
}

extern "C" void kernel_launch(void* const* d_in, const int* in_sizes, int n_in,
                              void* d_out, int out_size, void* d_ws, size_t ws_size,
                              hipStream_t stream) {
    const float* x = (const float*)d_in[0];
    const float* off = (const float*)d_in[1];
    const float* w = (const float*)d_in[2];
    float* out = (float*)d_out;

    char* ws = (char*)d_ws;
    unsigned short* bp = (unsigned short*)ws;                       //      73,728 B
    unsigned short* xt = (unsigned short*)(ws + 73728);             //  16,777,216 B
    unsigned* metap = (unsigned*)(ws + 16850944);                   //   4,718,592 B
    unsigned* w01p  = (unsigned*)(ws + 21569536);                   //   4,718,592 B
    unsigned* w23p  = (unsigned*)(ws + 26288128);                   //   4,718,592 B -> 31.0 MB

    prep_all<<<8848, 256, 0, stream>>>(x, off, w, xt, bp, metap, w01p, w23p);
    dcn_mfma<<<1024, 512, 0, stream>>>(xt, metap, w01p, w23p, bp, out);
}